// Round 11
// baseline (459.969 us; speedup 1.0000x reference)
//
#include <hip/hip_runtime.h>

constexpr int TPB  = 256;
constexpr int TPBW = 1024;
constexpr int PH   = 256;              // row-hist slices
constexpr int PS   = 512;              // col/stage slices (2 blocks/CU)
constexpr int BSH  = 7;                // 128-node buckets
constexpr int BKN  = 128;
constexpr int MAXB = 800;              // max buckets (N <= 102400)
constexpr int HWL  = 12800;            // nibble hist words (N <= 102400)
constexpr int SBUF = 4608;             // per-bucket LDS segment capacity
constexpr int ITER = 6;                // ceil(SBUF/TPBW)+1

// ---------------------------------------------- per-slice col bucket counts
__global__ void k_cnt(const int* __restrict__ col, int E, int sliceLen,
                      int* __restrict__ cntTab, int NBKT) {
    __shared__ int cl[MAXB];
    const int p = blockIdx.x;
    for (int t = threadIdx.x; t < NBKT; t += TPB) cl[t] = 0;
    __syncthreads();
    const int s = p * sliceLen, send = min(s + sliceLen, E);
    for (int e = s + threadIdx.x; e < send; e += TPB)
        atomicAdd(&cl[col[e] >> BSH], 1);
    __syncthreads();
    for (int b = threadIdx.x; b < NBKT; b += TPB) cntTab[b * PS + p] = cl[b];
}

// ---------------------------------------------- nibble row histogram (degree)
__global__ __launch_bounds__(TPBW)
void k_hist(const int* __restrict__ row, int E, int sliceLen,
            unsigned int* __restrict__ partialR, int W) {
    __shared__ unsigned int lh[HWL];
    const int p = blockIdx.x;
    for (int t = threadIdx.x; t < W; t += TPBW) lh[t] = 0;
    __syncthreads();
    const int s = p * sliceLen, send = min(s + sliceLen, E);
    for (int e = s + threadIdx.x; e < send; e += TPBW) {
        int v = row[e];
        atomicAdd(&lh[v >> 3], 1u << ((v & 7) * 4));
    }
    __syncthreads();
    for (int w = threadIdx.x; w < W; w += TPBW)
        partialR[(size_t)p * W + w] = lh[w];
}

// ---------------------------------------------- hierarchical scan of cntTab
__global__ void k_scanB1(int* __restrict__ tab, int total, int* __restrict__ bs) {
    __shared__ int tmp[2][1024];
    const int t = threadIdx.x, idx = blockIdx.x * 1024 + t;
    int v = (idx < total) ? tab[idx] : 0;
    int buf = 0;
    tmp[0][t] = v;
    __syncthreads();
    for (int off = 1; off < 1024; off <<= 1) {
        int nv = tmp[buf][t] + ((t >= off) ? tmp[buf][t - off] : 0);
        buf ^= 1; tmp[buf][t] = nv;
        __syncthreads();
    }
    int incl = tmp[buf][t];
    if (idx < total) tab[idx] = incl - v;
    if (t == 1023) bs[blockIdx.x] = incl;
}

__global__ void k_scan2(int* __restrict__ bsum, int NB) {
    __shared__ int tmp[2][256];
    __shared__ int carry_s;
    int t = threadIdx.x;
    if (t == 0) carry_s = 0;
    __syncthreads();
    for (int chunk = 0; chunk < NB; chunk += 256) {
        int idx = chunk + t;
        int v = (idx < NB) ? bsum[idx] : 0;
        int buf = 0;
        tmp[0][t] = v;
        __syncthreads();
        for (int off = 1; off < 256; off <<= 1) {
            int nv = tmp[buf][t] + ((t >= off) ? tmp[buf][t - off] : 0);
            buf ^= 1; tmp[buf][t] = nv;
            __syncthreads();
        }
        int incl = tmp[buf][t];
        int carry = carry_s;
        if (idx < NB) bsum[idx] = carry + incl - v;
        __syncthreads();
        if (t == 255) carry_s = carry + incl;
        __syncthreads();
    }
}

__global__ void k_scanB3(int* __restrict__ tab, int total, const int* __restrict__ bs,
                         int* __restrict__ segBase, int NBKT, int E) {
    const int idx = blockIdx.x * 1024 + threadIdx.x;
    if (idx < total) {
        int v = tab[idx] + bs[blockIdx.x];
        tab[idx] = v;
        if ((idx & (PS - 1)) == 0) segBase[idx / PS] = v;
    }
    if (idx == 0) segBase[NBKT] = E;
}

// ---------------------------------------------- reduce row partials -> dis
__global__ void k_disr(const unsigned int* __restrict__ partialR, int W, int N,
                       float* __restrict__ dis) {
    const int w = blockIdx.x * blockDim.x + threadIdx.x;
    if (w >= W) return;
    const unsigned int* pr = partialR + w;
    unsigned int accA = 0, accB = 0;            // byte lanes, totals <= ~66
    for (int p = 0; p < PH; p++) {
        unsigned int v = pr[(size_t)p * W];
        accA += v & 0x0F0F0F0Fu;
        accB += (v >> 4) & 0x0F0F0F0Fu;
    }
    int d[8];
    d[0] = accA & 255; d[2] = (accA >> 8) & 255;
    d[4] = (accA >> 16) & 255; d[6] = accA >> 24;
    d[1] = accB & 255; d[3] = (accB >> 8) & 255;
    d[5] = (accB >> 16) & 255; d[7] = accB >> 24;
    const int n0 = w * 8;
#pragma unroll
    for (int k = 0; k < 8; k++)
        if (n0 + k < N) dis[n0 + k] = d[k] ? rsqrtf((float)d[k]) : 0.f;
}

// ------------------------ stage into bucket-major runs (two 8B streams)
__global__ __launch_bounds__(TPBW)
void k_stage(const int* __restrict__ ei, const float2* __restrict__ ea,
             const float* __restrict__ dis, int E, int sliceLen,
             const int* __restrict__ cntTab, int NBKT,
             int2* __restrict__ sa, float2* __restrict__ sb) {
    __shared__ int lb[MAXB], lbase[MAXB];
    const int p = blockIdx.x;
    for (int t = threadIdx.x; t < NBKT; t += TPBW) {
        lb[t] = 0;
        lbase[t] = cntTab[t * PS + p];
    }
    __syncthreads();
    const int* colA = ei + E;
    const int s = p * sliceLen, send = min(s + sliceLen, E);
    for (int e = s + threadIdx.x; e < send; e += TPBW) {
        int c = colA[e], r = ei[e];
        int b = c >> BSH;
        float nrm = dis[r] * dis[c];
        int pos = lbase[b] + atomicAdd(&lb[b], 1);
        float2 ev = ea[e];
        sa[pos] = make_int2((r << BSH) | (c & (BKN - 1)), __float_as_int(nrm));
        sb[pos] = make_float2(nrm * ev.x, nrm * ev.y);
    }
}

// ---------- sortA: in-LDS counting sort + ea sums + fused layer-1 -> h
__global__ __launch_bounds__(TPBW)
void k_sortA(const int2* __restrict__ sa, const float2* __restrict__ sb,
             const int* __restrict__ segBase, const float* __restrict__ x, int N,
             const float* __restrict__ Wc, const float* __restrict__ bc,
             const float* __restrict__ Wn,
             float* __restrict__ h, float2* __restrict__ eaS) {
    __shared__ int2 sbuf[SBUF];
    __shared__ int lfill[BKN], lexc[BKN], tmp[2][BKN];
    __shared__ float lacx[BKN], lacy[BKN];
    __shared__ float sax[BKN], say[BKN], saz[BKN];
    __shared__ float sWc[48], sbc[16], sWn[80];
    const int b = blockIdx.x, t = threadIdx.x;
    const int s0 = segBase[b], s1 = segBase[b + 1], c0 = b << BSH;
    if (t < BKN) { lfill[t] = 0; lacx[t] = 0.f; lacy[t] = 0.f; }
    if (t < 48) sWc[t] = Wc[t];
    if (t >= 64 && t < 80) sbc[t - 64] = bc[t - 64];
    if (t >= 128 && t < 208) sWn[t - 128] = Wn[t - 128];
    __syncthreads();
    int2 rv[ITER]; int rk[ITER]; int nIt = 0;
    for (int e = s0 + t; e < s1; e += TPBW) {
        if (nIt < ITER) {
            int2 v = sa[e];
            float2 w = sb[e];
            int j = v.x & (BKN - 1);
            rv[nIt] = v;
            rk[nIt] = atomicAdd(&lfill[j], 1);
            nIt++;
            unsafeAtomicAdd(&lacx[j], w.x);
            unsafeAtomicAdd(&lacy[j], w.y);
        }
    }
    __syncthreads();
    int buf = 0;
    if (t < BKN) tmp[0][t] = lfill[t];
    __syncthreads();
    for (int off = 1; off < BKN; off <<= 1) {
        if (t < BKN) {
            int nv = tmp[buf][t] + ((t >= off) ? tmp[buf][t - off] : 0);
            tmp[buf ^ 1][t] = nv;
        }
        __syncthreads();
        buf ^= 1;
    }
    if (t < BKN) lexc[t] = tmp[buf][t] - lfill[t];
    __syncthreads();
    for (int k = 0; k < nIt; k++) {
        int2 v = rv[k];
        int j = v.x & (BKN - 1);
        int pos = lexc[j] + rk[k];
        if (pos < SBUF) sbuf[pos] = make_int2(((unsigned)v.x) >> BSH, v.y);
    }
    __syncthreads();
    // owner-walk: 8 threads per node, x-gathers + shfl reduce
    const int grp = t >> 3, sub = t & 7;
    const int node = c0 + grp;
    float a0 = 0.f, a1 = 0.f, a2 = 0.f;
    if (node < N) {
        int e0 = lexc[grp], dg = lfill[grp];
        for (int e = sub; e < dg; e += 8) {
            int2 s = sbuf[e0 + e];
            float nrm = __int_as_float(s.y);
            const float* xr = x + 3 * (long)s.x;
            a0 += nrm * xr[0];
            a1 += nrm * xr[1];
            a2 += nrm * xr[2];
        }
    }
    a0 += __shfl_down(a0, 4, 8); a0 += __shfl_down(a0, 2, 8); a0 += __shfl_down(a0, 1, 8);
    a1 += __shfl_down(a1, 4, 8); a1 += __shfl_down(a1, 2, 8); a1 += __shfl_down(a1, 1, 8);
    a2 += __shfl_down(a2, 4, 8); a2 += __shfl_down(a2, 2, 8); a2 += __shfl_down(a2, 1, 8);
    if (sub == 0) { sax[grp] = a0; say[grp] = a1; saz[grp] = a2; }
    __syncthreads();
    if (t < BKN) {
        int nd = c0 + t;
        if (nd < N) {
            float inv = 1.0f / fmaxf((float)lfill[t], 1.0f);
            float m[5] = {sax[t] * inv, say[t] * inv, saz[t] * inv,
                          lacx[t] * inv, lacy[t] * inv};
            float xv[3];
#pragma unroll
            for (int j = 0; j < 3; j++) xv[j] = x[3 * (long)nd + j];
            float o[16];
#pragma unroll
            for (int k = 0; k < 16; k++) {
                float v = sbc[k];
#pragma unroll
                for (int j = 0; j < 3; j++) v += xv[j] * sWc[j * 16 + k];
#pragma unroll
                for (int j = 0; j < 5; j++) v += m[j] * sWn[j * 16 + k];
                o[k] = fmaxf(v, 0.0f);
            }
            float4* hp = (float4*)(h + 16 * (long)nd);
#pragma unroll
            for (int q = 0; q < 4; q++)
                hp[q] = make_float4(o[4 * q], o[4 * q + 1], o[4 * q + 2], o[4 * q + 3]);
            eaS[nd] = make_float2(lacx[t], lacy[t]);
        }
    }
}

// ---- g2: re-sort in LDS + h owner-walk + node update + pooling (fused)
__global__ __launch_bounds__(TPBW)
void k_g2(const int2* __restrict__ sa, const int* __restrict__ segBase,
          const float* __restrict__ h, const float2* __restrict__ eaS,
          const int* __restrict__ batch, int N,
          const float* __restrict__ Wc, const float* __restrict__ bc,
          const float* __restrict__ Wn,
          float* __restrict__ pool, int* __restrict__ poolcnt) {
    __shared__ int2 sbuf[SBUF];
    __shared__ int lfill[BKN], lexc[BKN], tmp[2][BKN];
    __shared__ float smr[BKN][17];
    __shared__ float sWc[256], sbc[16], sWn[288], sp[1024];
    __shared__ int sc[64];
    const int b = blockIdx.x, t = threadIdx.x;
    const int s0 = segBase[b], s1 = segBase[b + 1], c0 = b << BSH;
    if (t < BKN) lfill[t] = 0;
    for (int k = t; k < 256; k += TPBW) sWc[k] = Wc[k];
    for (int k = t; k < 16;  k += TPBW) sbc[k] = bc[k];
    for (int k = t; k < 288; k += TPBW) sWn[k] = Wn[k];
    for (int k = t; k < 1024; k += TPBW) sp[k] = 0.f;
    if (t < 64) sc[t] = 0;
    __syncthreads();
    int2 rv[ITER]; int rk[ITER]; int nIt = 0;
    for (int e = s0 + t; e < s1; e += TPBW) {
        if (nIt < ITER) {
            int2 v = sa[e];
            rv[nIt] = v;
            rk[nIt] = atomicAdd(&lfill[v.x & (BKN - 1)], 1);
            nIt++;
        }
    }
    __syncthreads();
    int buf = 0;
    if (t < BKN) tmp[0][t] = lfill[t];
    __syncthreads();
    for (int off = 1; off < BKN; off <<= 1) {
        if (t < BKN) {
            int nv = tmp[buf][t] + ((t >= off) ? tmp[buf][t - off] : 0);
            tmp[buf ^ 1][t] = nv;
        }
        __syncthreads();
        buf ^= 1;
    }
    if (t < BKN) lexc[t] = tmp[buf][t] - lfill[t];
    __syncthreads();
    for (int k = 0; k < nIt; k++) {
        int2 v = rv[k];
        int j = v.x & (BKN - 1);
        int pos = lexc[j] + rk[k];
        if (pos < SBUF) sbuf[pos] = make_int2(((unsigned)v.x) >> BSH, v.y);
    }
    __syncthreads();
    // owner-walk: 8 threads per node, h-gathers + shfl reduce
    const int grp = t >> 3, sub = t & 7;
    const int node = c0 + grp;
    float mm[16];
#pragma unroll
    for (int k = 0; k < 16; k++) mm[k] = 0.f;
    if (node < N) {
        int e0 = lexc[grp], dg = lfill[grp];
        for (int e = sub; e < dg; e += 8) {
            int2 s = sbuf[e0 + e];
            float nrm = __int_as_float(s.y);
            const float4* hr = (const float4*)(h + 16 * (long)s.x);
            float4 h0 = hr[0], h1 = hr[1], h2 = hr[2], h3 = hr[3];
            mm[0]  += nrm * h0.x;  mm[1]  += nrm * h0.y;
            mm[2]  += nrm * h0.z;  mm[3]  += nrm * h0.w;
            mm[4]  += nrm * h1.x;  mm[5]  += nrm * h1.y;
            mm[6]  += nrm * h1.z;  mm[7]  += nrm * h1.w;
            mm[8]  += nrm * h2.x;  mm[9]  += nrm * h2.y;
            mm[10] += nrm * h2.z;  mm[11] += nrm * h2.w;
            mm[12] += nrm * h3.x;  mm[13] += nrm * h3.y;
            mm[14] += nrm * h3.z;  mm[15] += nrm * h3.w;
        }
    }
#pragma unroll
    for (int k = 0; k < 16; k++) {
        mm[k] += __shfl_down(mm[k], 4, 8);
        mm[k] += __shfl_down(mm[k], 2, 8);
        mm[k] += __shfl_down(mm[k], 1, 8);
    }
    if (sub == 0) {
#pragma unroll
        for (int k = 0; k < 16; k++) smr[grp][k] = mm[k];
    }
    __syncthreads();
    if (t < BKN) {
        int nd = c0 + t;
        if (nd < N) {
            float inv = 1.0f / fmaxf((float)lfill[t], 1.0f);
            float m[18];
#pragma unroll
            for (int k = 0; k < 16; k++) m[k] = smr[t][k] * inv;
            float2 es = eaS[nd];
            m[16] = es.x * inv; m[17] = es.y * inv;
            float hv[16];
            const float4* hp = (const float4*)(h + 16 * (long)nd);
#pragma unroll
            for (int q = 0; q < 4; q++) {
                float4 t4 = hp[q];
                hv[4 * q] = t4.x; hv[4 * q + 1] = t4.y;
                hv[4 * q + 2] = t4.z; hv[4 * q + 3] = t4.w;
            }
            int g = batch[nd];
            atomicAdd(&sc[g], 1);
#pragma unroll
            for (int k = 0; k < 16; k++) {
                float v = sbc[k];
#pragma unroll
                for (int j = 0; j < 16; j++) v += hv[j] * sWc[j * 16 + k];
#pragma unroll
                for (int j = 0; j < 18; j++) v += m[j] * sWn[j * 16 + k];
                v = fmaxf(v, 0.0f);
                unsafeAtomicAdd(&sp[g * 16 + k], v);
            }
        }
    }
    __syncthreads();
    for (int k = t; k < 1024; k += TPBW)
        if (sp[k] != 0.0f) unsafeAtomicAdd(&pool[k], sp[k]);
    if (t < 64 && sc[t]) atomicAdd(&poolcnt[t], sc[t]);
}

// ---------------------------------------------------------------- MLP head
__global__ void k_final(const float* __restrict__ pool, const int* __restrict__ poolcnt,
                        const float* __restrict__ Wl1, const float* __restrict__ bl1,
                        const float* __restrict__ Wl2, const float* __restrict__ bl2,
                        float* __restrict__ out) {
    int g = threadIdx.x;
    if (g >= 64) return;
    float inv = 1.0f / fmaxf((float)poolcnt[g], 1.0f);
    float gv[16];
#pragma unroll
    for (int k = 0; k < 16; k++) gv[k] = pool[g * 16 + k] * inv;
    float t[16];
#pragma unroll
    for (int k = 0; k < 16; k++) {
        float v = bl1[k];
#pragma unroll
        for (int j = 0; j < 16; j++) v += gv[j] * Wl1[j * 16 + k];
        t[k] = fmaxf(v, 0.0f);
    }
    float o0 = bl2[0], o1 = bl2[1];
#pragma unroll
    for (int j = 0; j < 16; j++) {
        o0 += t[j] * Wl2[j * 2 + 0];
        o1 += t[j] * Wl2[j * 2 + 1];
    }
    out[2 * g + 0] = o0;
    out[2 * g + 1] = o1;
}

extern "C" void kernel_launch(void* const* d_in, const int* in_sizes, int n_in,
                              void* d_out, int out_size, void* d_ws, size_t ws_size,
                              hipStream_t stream) {
    const float* x     = (const float*)d_in[0];
    const int*   ei    = (const int*)  d_in[1];
    const float* ea    = (const float*)d_in[2];
    const int*   batch = (const int*)  d_in[3];
    const float* Wc1   = (const float*)d_in[4];
    const float* bc1   = (const float*)d_in[5];
    const float* Wn1   = (const float*)d_in[6];
    const float* Wc2   = (const float*)d_in[7];
    const float* bc2   = (const float*)d_in[8];
    const float* Wn2   = (const float*)d_in[9];
    const float* Wl1   = (const float*)d_in[10];
    const float* bl1   = (const float*)d_in[11];
    const float* Wl2   = (const float*)d_in[12];
    const float* bl2   = (const float*)d_in[13];
    float* out = (float*)d_out;

    const int N  = in_sizes[0] / 3;
    const int E  = in_sizes[1] / 2;
    const int NBKT = (N + BKN - 1) >> BSH;        // <= 800 for N <= 102400
    const int W  = (N + 7) >> 3;                  // <= 12800
    const int total = NBKT * PS;
    const int NSB = (total + 1023) / 1024;
    const int sliceH = (E + PH - 1) / PH;
    const int sliceS = (E + PS - 1) / PS;

    char* ws = (char*)d_ws;
    size_t o = 0;
    auto alloc = [&](size_t bytes) {
        void* p = ws + o;
        o += (bytes + 255) & ~(size_t)255;
        return p;
    };
    // zeroed region (pool + poolcnt only)
    float* pool    = (float*)alloc(64 * 16 * 4);
    int*   poolcnt = (int*)  alloc(64 * 4);
    size_t zbytes = o;
    // non-zeroed
    float*  dis     = (float*)alloc((size_t)N * 4);
    float2* eaS     = (float2*)alloc((size_t)N * 8);
    int*    cntTab  = (int*)  alloc((size_t)total * 4);
    int*    bs      = (int*)  alloc((size_t)NSB * 4);
    int*    segBase = (int*)  alloc((size_t)(NBKT + 1) * 4);
    // region A: partialR [hist..disr] then h [sortA..g2]
    size_t szPR = (size_t)PH * W * 4, szH = (size_t)N * 16 * 4;
    char* regionA = (char*)alloc(szPR > szH ? szPR : szH);
    unsigned int* partialR = (unsigned int*)regionA;
    float* h = (float*)regionA;
    int2*   sa = (int2*)  alloc((size_t)E * 8);
    float2* sb = (float2*)alloc((size_t)E * 8);
    (void)ws_size;

    hipMemsetAsync(d_ws, 0, zbytes, stream);

    k_cnt   <<<PS, TPB, 0, stream>>>(ei + E, E, sliceS, cntTab, NBKT);
    k_hist  <<<PH, TPBW, 0, stream>>>(ei, E, sliceH, partialR, W);
    k_scanB1<<<NSB, 1024, 0, stream>>>(cntTab, total, bs);
    k_scan2 <<<1, 256, 0, stream>>>(bs, NSB);
    k_scanB3<<<NSB, 1024, 0, stream>>>(cntTab, total, bs, segBase, NBKT, E);
    k_disr  <<<(W + TPB - 1) / TPB, TPB, 0, stream>>>(partialR, W, N, dis);
    k_stage <<<PS, TPBW, 0, stream>>>(ei, (const float2*)ea, dis, E, sliceS,
                                      cntTab, NBKT, sa, sb);
    k_sortA <<<NBKT, TPBW, 0, stream>>>(sa, sb, segBase, x, N,
                                        Wc1, bc1, Wn1, h, eaS);
    k_g2    <<<NBKT, TPBW, 0, stream>>>(sa, segBase, h, eaS, batch, N,
                                        Wc2, bc2, Wn2, pool, poolcnt);
    k_final <<<1, 64, 0, stream>>>(pool, poolcnt, Wl1, bl1, Wl2, bl2, out);
}

// Round 12
// 386.609 us; speedup vs baseline: 1.1898x; 1.1898x over previous
//
#include <hip/hip_runtime.h>

constexpr int TPB  = 256;
constexpr int TPBW = 1024;
constexpr int PS   = 256;              // slices (1 block/CU for stage: long runs)
constexpr int BSH  = 7;                // 128-node buckets
constexpr int BKN  = 128;
constexpr int MAXB = 800;              // max buckets (N <= 102400)
constexpr int HWL  = 12800;            // nibble hist words (N <= 102400)
constexpr int SBUF = 4608;             // per-bucket LDS segment capacity
constexpr int ITER = 6;

// ---------------- fused: per-slice col bucket counts + row nibble histogram
__global__ __launch_bounds__(TPBW)
void k_prep2(const int* __restrict__ ei, int E, int sliceLen, int W, int NBKT,
             unsigned int* __restrict__ partialR, int* __restrict__ cntTab) {
    __shared__ unsigned int lh[HWL];
    __shared__ int cl[MAXB];
    const int p = blockIdx.x;
    for (int t = threadIdx.x; t < W; t += TPBW) lh[t] = 0;
    for (int t = threadIdx.x; t < NBKT; t += TPBW) cl[t] = 0;
    __syncthreads();
    const int* colA = ei + E;
    const int s = p * sliceLen, send = min(s + sliceLen, E);
    for (int e = s + threadIdx.x; e < send; e += TPBW) {
        int r = ei[e], c = colA[e];
        atomicAdd(&lh[r >> 3], 1u << ((r & 7) * 4));   // per-slice count <= ~7 < 15
        atomicAdd(&cl[c >> BSH], 1);
    }
    __syncthreads();
    for (int w = threadIdx.x; w < W; w += TPBW) partialR[(size_t)p * W + w] = lh[w];
    for (int b = threadIdx.x; b < NBKT; b += TPBW) cntTab[b * PS + p] = cl[b];
}

// ---------------------------------------------- hierarchical scan of cntTab
__global__ void k_scanB1(int* __restrict__ tab, int total, int* __restrict__ bs) {
    __shared__ int tmp[2][1024];
    const int t = threadIdx.x, idx = blockIdx.x * 1024 + t;
    int v = (idx < total) ? tab[idx] : 0;
    int buf = 0;
    tmp[0][t] = v;
    __syncthreads();
    for (int off = 1; off < 1024; off <<= 1) {
        int nv = tmp[buf][t] + ((t >= off) ? tmp[buf][t - off] : 0);
        buf ^= 1; tmp[buf][t] = nv;
        __syncthreads();
    }
    int incl = tmp[buf][t];
    if (idx < total) tab[idx] = incl - v;
    if (t == 1023) bs[blockIdx.x] = incl;
}

__global__ void k_scan2(int* __restrict__ bsum, int NB) {
    __shared__ int tmp[2][256];
    __shared__ int carry_s;
    int t = threadIdx.x;
    if (t == 0) carry_s = 0;
    __syncthreads();
    for (int chunk = 0; chunk < NB; chunk += 256) {
        int idx = chunk + t;
        int v = (idx < NB) ? bsum[idx] : 0;
        int buf = 0;
        tmp[0][t] = v;
        __syncthreads();
        for (int off = 1; off < 256; off <<= 1) {
            int nv = tmp[buf][t] + ((t >= off) ? tmp[buf][t - off] : 0);
            buf ^= 1; tmp[buf][t] = nv;
            __syncthreads();
        }
        int incl = tmp[buf][t];
        int carry = carry_s;
        if (idx < NB) bsum[idx] = carry + incl - v;
        __syncthreads();
        if (t == 255) carry_s = carry + incl;
        __syncthreads();
    }
}

__global__ void k_scanB3(int* __restrict__ tab, int total, const int* __restrict__ bs,
                         int* __restrict__ segBase, int NBKT, int E) {
    const int idx = blockIdx.x * 1024 + threadIdx.x;
    if (idx < total) {
        int v = tab[idx] + bs[blockIdx.x];
        tab[idx] = v;
        if ((idx & (PS - 1)) == 0) segBase[idx / PS] = v;
    }
    if (idx == 0) segBase[NBKT] = E;
}

// ---------------------------------------------- reduce row partials -> dis
__global__ void k_disr(const unsigned int* __restrict__ partialR, int W, int N,
                       float* __restrict__ dis) {
    const int w = blockIdx.x * blockDim.x + threadIdx.x;
    if (w >= W) return;
    const unsigned int* pr = partialR + w;
    unsigned int accA = 0, accB = 0;            // byte lanes, totals <= ~66
    for (int p = 0; p < PS; p++) {
        unsigned int v = pr[(size_t)p * W];
        accA += v & 0x0F0F0F0Fu;
        accB += (v >> 4) & 0x0F0F0F0Fu;
    }
    int d[8];
    d[0] = accA & 255; d[2] = (accA >> 8) & 255;
    d[4] = (accA >> 16) & 255; d[6] = accA >> 24;
    d[1] = accB & 255; d[3] = (accB >> 8) & 255;
    d[5] = (accB >> 16) & 255; d[7] = accB >> 24;
    const int n0 = w * 8;
#pragma unroll
    for (int k = 0; k < 8; k++)
        if (n0 + k < N) dis[n0 + k] = d[k] ? rsqrtf((float)d[k]) : 0.f;
}

// ------------------------------- stage into bucket-major runs (16B records)
__global__ __launch_bounds__(TPBW)
void k_stage(const int* __restrict__ ei, const float2* __restrict__ ea,
             const float* __restrict__ dis, int E, int sliceLen,
             const int* __restrict__ cntTab, int NBKT, int4* __restrict__ staged) {
    __shared__ int lb[MAXB], lbase[MAXB];
    const int p = blockIdx.x;
    for (int t = threadIdx.x; t < NBKT; t += TPBW) {
        lb[t] = 0;
        lbase[t] = cntTab[t * PS + p];
    }
    __syncthreads();
    const int* colA = ei + E;
    const int s = p * sliceLen, send = min(s + sliceLen, E);
    for (int e = s + threadIdx.x; e < send; e += TPBW) {
        int c = colA[e], r = ei[e];
        int b = c >> BSH;
        float nrm = dis[r] * dis[c];
        int pos = lbase[b] + atomicAdd(&lb[b], 1);
        float2 ev = ea[e];
        staged[pos] = make_int4((r << BSH) | (c & (BKN - 1)), __float_as_int(nrm),
                                __float_as_int(nrm * ev.x), __float_as_int(nrm * ev.y));
    }
}

// --- sortA: in-LDS counting sort + ea sums + fused layer-1 -> h,
//     then sequential sorted-rec writeout (full-line writebacks) + cnt
__global__ __launch_bounds__(TPBW)
void k_sortA(const int4* __restrict__ staged, const int* __restrict__ segBase,
             const float* __restrict__ x, int N,
             const float* __restrict__ Wc, const float* __restrict__ bc,
             const float* __restrict__ Wn,
             float* __restrict__ h, float2* __restrict__ eaS,
             int* __restrict__ cnt, int2* __restrict__ rec) {
    __shared__ int2 sbuf[SBUF];
    __shared__ int lfill[BKN], lexc[BKN], tmp[2][BKN];
    __shared__ float lacx[BKN], lacy[BKN];
    __shared__ float sax[BKN], say[BKN], saz[BKN];
    __shared__ float sWc[48], sbc[16], sWn[80];
    const int b = blockIdx.x, t = threadIdx.x;
    const int s0 = segBase[b], s1 = segBase[b + 1], c0 = b << BSH;
    if (t < BKN) { lfill[t] = 0; lacx[t] = 0.f; lacy[t] = 0.f; }
    if (t < 48) sWc[t] = Wc[t];
    if (t >= 64 && t < 80) sbc[t - 64] = bc[t - 64];
    if (t >= 128 && t < 208) sWn[t - 128] = Wn[t - 128];
    __syncthreads();
    int4 rv[ITER]; int rk[ITER]; int nIt = 0;
    for (int e = s0 + t; e < s1; e += TPBW) {
        if (nIt < ITER) {
            int4 v = staged[e];
            int j = v.x & (BKN - 1);
            rv[nIt] = v;
            rk[nIt] = atomicAdd(&lfill[j], 1);
            nIt++;
            unsafeAtomicAdd(&lacx[j], __int_as_float(v.z));
            unsafeAtomicAdd(&lacy[j], __int_as_float(v.w));
        }
    }
    __syncthreads();
    int buf = 0;
    if (t < BKN) tmp[0][t] = lfill[t];
    __syncthreads();
    for (int off = 1; off < BKN; off <<= 1) {
        if (t < BKN) {
            int nv = tmp[buf][t] + ((t >= off) ? tmp[buf][t - off] : 0);
            tmp[buf ^ 1][t] = nv;
        }
        __syncthreads();
        buf ^= 1;
    }
    if (t < BKN) lexc[t] = tmp[buf][t] - lfill[t];
    __syncthreads();
    for (int k = 0; k < nIt; k++) {
        int4 v = rv[k];
        int j = v.x & (BKN - 1);
        int pos = lexc[j] + rk[k];
        int2 o = make_int2(((unsigned)v.x) >> BSH, v.y);
        if (pos < SBUF) sbuf[pos] = o;
        else rec[s0 + pos] = o;                    // statistically impossible
    }
    __syncthreads();
    // owner-walk: 8 threads per node, x-gathers + shfl reduce
    const int grp = t >> 3, sub = t & 7;
    const int node = c0 + grp;
    float a0 = 0.f, a1 = 0.f, a2 = 0.f;
    if (node < N) {
        int e0 = lexc[grp], dg = lfill[grp];
        for (int e = sub; e < dg; e += 8) {
            int2 s = sbuf[e0 + e];
            float nrm = __int_as_float(s.y);
            const float* xr = x + 3 * (long)s.x;
            a0 += nrm * xr[0];
            a1 += nrm * xr[1];
            a2 += nrm * xr[2];
        }
    }
    a0 += __shfl_down(a0, 4, 8); a0 += __shfl_down(a0, 2, 8); a0 += __shfl_down(a0, 1, 8);
    a1 += __shfl_down(a1, 4, 8); a1 += __shfl_down(a1, 2, 8); a1 += __shfl_down(a1, 1, 8);
    a2 += __shfl_down(a2, 4, 8); a2 += __shfl_down(a2, 2, 8); a2 += __shfl_down(a2, 1, 8);
    if (sub == 0) { sax[grp] = a0; say[grp] = a1; saz[grp] = a2; }
    __syncthreads();
    if (t < BKN) {
        int nd = c0 + t;
        if (nd < N) {
            float inv = 1.0f / fmaxf((float)lfill[t], 1.0f);
            float m[5] = {sax[t] * inv, say[t] * inv, saz[t] * inv,
                          lacx[t] * inv, lacy[t] * inv};
            float xv[3];
#pragma unroll
            for (int j = 0; j < 3; j++) xv[j] = x[3 * (long)nd + j];
            float o[16];
#pragma unroll
            for (int k = 0; k < 16; k++) {
                float v = sbc[k];
#pragma unroll
                for (int j = 0; j < 3; j++) v += xv[j] * sWc[j * 16 + k];
#pragma unroll
                for (int j = 0; j < 5; j++) v += m[j] * sWn[j * 16 + k];
                o[k] = fmaxf(v, 0.0f);
            }
            float4* hp = (float4*)(h + 16 * (long)nd);
#pragma unroll
            for (int q = 0; q < 4; q++)
                hp[q] = make_float4(o[4 * q], o[4 * q + 1], o[4 * q + 2], o[4 * q + 3]);
            eaS[nd] = make_float2(lacx[t], lacy[t]);
            cnt[nd] = lfill[t];
        }
    }
    __syncthreads();
    const int len = s1 - s0;
    for (int k = t; k < len && k < SBUF; k += TPBW) rec[s0 + k] = sbuf[k];
}

// ---- g2: direct global CSR owner-walk (rec is sorted) + node update + pooling
__global__ __launch_bounds__(TPBW)
void k_g2(const int2* __restrict__ rec, const int* __restrict__ segBase,
          const int* __restrict__ cnt, const float* __restrict__ h,
          const float2* __restrict__ eaS, const int* __restrict__ batch, int N,
          const float* __restrict__ Wc, const float* __restrict__ bc,
          const float* __restrict__ Wn,
          float* __restrict__ pool, int* __restrict__ poolcnt) {
    __shared__ int lcnt[BKN], lexc[BKN], tmp[2][BKN];
    __shared__ float smr[BKN][17];
    __shared__ float sWc[256], sbc[16], sWn[288], sp[1024];
    __shared__ int sc[64];
    const int b = blockIdx.x, t = threadIdx.x;
    const int s0 = segBase[b], c0 = b << BSH;
    if (t < BKN) lcnt[t] = (c0 + t < N) ? cnt[c0 + t] : 0;
    for (int k = t; k < 256; k += TPBW) sWc[k] = Wc[k];
    for (int k = t; k < 16;  k += TPBW) sbc[k] = bc[k];
    for (int k = t; k < 288; k += TPBW) sWn[k] = Wn[k];
    for (int k = t; k < 1024; k += TPBW) sp[k] = 0.f;
    if (t < 64) sc[t] = 0;
    __syncthreads();
    int buf = 0;
    if (t < BKN) tmp[0][t] = lcnt[t];
    __syncthreads();
    for (int off = 1; off < BKN; off <<= 1) {
        if (t < BKN) {
            int nv = tmp[buf][t] + ((t >= off) ? tmp[buf][t - off] : 0);
            tmp[buf ^ 1][t] = nv;
        }
        __syncthreads();
        buf ^= 1;
    }
    if (t < BKN) lexc[t] = tmp[buf][t] - lcnt[t];
    __syncthreads();
    // owner-walk straight from global sorted rec (coalesced per 8-group)
    const int grp = t >> 3, sub = t & 7;
    const int node = c0 + grp;
    float mm[16];
#pragma unroll
    for (int k = 0; k < 16; k++) mm[k] = 0.f;
    if (node < N) {
        const int2* rp = rec + s0 + lexc[grp];
        int dg = lcnt[grp];
        for (int e = sub; e < dg; e += 8) {
            int2 rv = rp[e];
            float nrm = __int_as_float(rv.y);
            const float4* hr = (const float4*)(h + 16 * (long)rv.x);
            float4 h0 = hr[0], h1 = hr[1], h2 = hr[2], h3 = hr[3];
            mm[0]  += nrm * h0.x;  mm[1]  += nrm * h0.y;
            mm[2]  += nrm * h0.z;  mm[3]  += nrm * h0.w;
            mm[4]  += nrm * h1.x;  mm[5]  += nrm * h1.y;
            mm[6]  += nrm * h1.z;  mm[7]  += nrm * h1.w;
            mm[8]  += nrm * h2.x;  mm[9]  += nrm * h2.y;
            mm[10] += nrm * h2.z;  mm[11] += nrm * h2.w;
            mm[12] += nrm * h3.x;  mm[13] += nrm * h3.y;
            mm[14] += nrm * h3.z;  mm[15] += nrm * h3.w;
        }
    }
#pragma unroll
    for (int k = 0; k < 16; k++) {
        mm[k] += __shfl_down(mm[k], 4, 8);
        mm[k] += __shfl_down(mm[k], 2, 8);
        mm[k] += __shfl_down(mm[k], 1, 8);
    }
    if (sub == 0) {
#pragma unroll
        for (int k = 0; k < 16; k++) smr[grp][k] = mm[k];
    }
    __syncthreads();
    if (t < BKN) {
        int nd = c0 + t;
        if (nd < N) {
            float inv = 1.0f / fmaxf((float)lcnt[t], 1.0f);
            float m[18];
#pragma unroll
            for (int k = 0; k < 16; k++) m[k] = smr[t][k] * inv;
            float2 es = eaS[nd];
            m[16] = es.x * inv; m[17] = es.y * inv;
            float hv[16];
            const float4* hp = (const float4*)(h + 16 * (long)nd);
#pragma unroll
            for (int q = 0; q < 4; q++) {
                float4 t4 = hp[q];
                hv[4 * q] = t4.x; hv[4 * q + 1] = t4.y;
                hv[4 * q + 2] = t4.z; hv[4 * q + 3] = t4.w;
            }
            int g = batch[nd];
            atomicAdd(&sc[g], 1);
#pragma unroll
            for (int k = 0; k < 16; k++) {
                float v = sbc[k];
#pragma unroll
                for (int j = 0; j < 16; j++) v += hv[j] * sWc[j * 16 + k];
#pragma unroll
                for (int j = 0; j < 18; j++) v += m[j] * sWn[j * 16 + k];
                v = fmaxf(v, 0.0f);
                unsafeAtomicAdd(&sp[g * 16 + k], v);
            }
        }
    }
    __syncthreads();
    for (int k = t; k < 1024; k += TPBW)
        if (sp[k] != 0.0f) unsafeAtomicAdd(&pool[k], sp[k]);
    if (t < 64 && sc[t]) atomicAdd(&poolcnt[t], sc[t]);
}

// ---------------------------------------------------------------- MLP head
__global__ void k_final(const float* __restrict__ pool, const int* __restrict__ poolcnt,
                        const float* __restrict__ Wl1, const float* __restrict__ bl1,
                        const float* __restrict__ Wl2, const float* __restrict__ bl2,
                        float* __restrict__ out) {
    int g = threadIdx.x;
    if (g >= 64) return;
    float inv = 1.0f / fmaxf((float)poolcnt[g], 1.0f);
    float gv[16];
#pragma unroll
    for (int k = 0; k < 16; k++) gv[k] = pool[g * 16 + k] * inv;
    float t[16];
#pragma unroll
    for (int k = 0; k < 16; k++) {
        float v = bl1[k];
#pragma unroll
        for (int j = 0; j < 16; j++) v += gv[j] * Wl1[j * 16 + k];
        t[k] = fmaxf(v, 0.0f);
    }
    float o0 = bl2[0], o1 = bl2[1];
#pragma unroll
    for (int j = 0; j < 16; j++) {
        o0 += t[j] * Wl2[j * 2 + 0];
        o1 += t[j] * Wl2[j * 2 + 1];
    }
    out[2 * g + 0] = o0;
    out[2 * g + 1] = o1;
}

extern "C" void kernel_launch(void* const* d_in, const int* in_sizes, int n_in,
                              void* d_out, int out_size, void* d_ws, size_t ws_size,
                              hipStream_t stream) {
    const float* x     = (const float*)d_in[0];
    const int*   ei    = (const int*)  d_in[1];
    const float* ea    = (const float*)d_in[2];
    const int*   batch = (const int*)  d_in[3];
    const float* Wc1   = (const float*)d_in[4];
    const float* bc1   = (const float*)d_in[5];
    const float* Wn1   = (const float*)d_in[6];
    const float* Wc2   = (const float*)d_in[7];
    const float* bc2   = (const float*)d_in[8];
    const float* Wn2   = (const float*)d_in[9];
    const float* Wl1   = (const float*)d_in[10];
    const float* bl1   = (const float*)d_in[11];
    const float* Wl2   = (const float*)d_in[12];
    const float* bl2   = (const float*)d_in[13];
    float* out = (float*)d_out;

    const int N  = in_sizes[0] / 3;
    const int E  = in_sizes[1] / 2;
    const int NBKT = (N + BKN - 1) >> BSH;        // <= 800 for N <= 102400
    const int W  = (N + 7) >> 3;                  // <= 12800
    const int total = NBKT * PS;
    const int NSB = (total + 1023) / 1024;
    const int sliceLen = (E + PS - 1) / PS;

    char* ws = (char*)d_ws;
    size_t o = 0;
    auto alloc = [&](size_t bytes) {
        void* p = ws + o;
        o += (bytes + 255) & ~(size_t)255;
        return p;
    };
    // zeroed region (pool + poolcnt only)
    float* pool    = (float*)alloc(64 * 16 * 4);
    int*   poolcnt = (int*)  alloc(64 * 4);
    size_t zbytes = o;
    // non-zeroed
    float*  dis     = (float*)alloc((size_t)N * 4);
    int*    cnt     = (int*)  alloc((size_t)N * 4);
    float2* eaS     = (float2*)alloc((size_t)N * 8);
    int*    cntTab  = (int*)  alloc((size_t)total * 4);
    int*    bs      = (int*)  alloc((size_t)NSB * 4);
    int*    segBase = (int*)  alloc((size_t)(NBKT + 1) * 4);
    // region B: partialR [prep2..disr] then rec [sortA..g2] (disjoint lifetimes)
    size_t szPR = (size_t)PS * W * 4, szRC = (size_t)E * 8;
    char* regionB = (char*)alloc(szPR > szRC ? szPR : szRC);
    unsigned int* partialR = (unsigned int*)regionB;
    int2* rec = (int2*)regionB;
    // staged: alive stage..sortA
    int4* staged = (int4*)alloc((size_t)E * 16);
    // h: written in sortA (while staged is read) -> own region
    float* h = (float*)alloc((size_t)N * 16 * 4);
    (void)ws_size;

    hipMemsetAsync(d_ws, 0, zbytes, stream);

    k_prep2 <<<PS, TPBW, 0, stream>>>(ei, E, sliceLen, W, NBKT, partialR, cntTab);
    k_scanB1<<<NSB, 1024, 0, stream>>>(cntTab, total, bs);
    k_scan2 <<<1, 256, 0, stream>>>(bs, NSB);
    k_scanB3<<<NSB, 1024, 0, stream>>>(cntTab, total, bs, segBase, NBKT, E);
    k_disr  <<<(W + TPB - 1) / TPB, TPB, 0, stream>>>(partialR, W, N, dis);
    k_stage <<<PS, TPBW, 0, stream>>>(ei, (const float2*)ea, dis, E, sliceLen,
                                      cntTab, NBKT, staged);
    k_sortA <<<NBKT, TPBW, 0, stream>>>(staged, segBase, x, N,
                                        Wc1, bc1, Wn1, h, eaS, cnt, rec);
    k_g2    <<<NBKT, TPBW, 0, stream>>>(rec, segBase, cnt, h, eaS, batch, N,
                                        Wc2, bc2, Wn2, pool, poolcnt);
    k_final <<<1, 64, 0, stream>>>(pool, poolcnt, Wl1, bl1, Wl2, bl2, out);
}

// Round 13
// 348.391 us; speedup vs baseline: 1.3203x; 1.1097x over previous
//
#include <hip/hip_runtime.h>

constexpr int TPB  = 256;
constexpr int TPBW = 1024;
constexpr int PS   = 256;              // edge slices (1 stage block/CU, long runs)
constexpr int BSH  = 8;                // 256-node buckets for staging/sort
constexpr int BKN  = 256;
constexpr int GKN  = 128;              // g2 nodes per block
constexpr int MAXB = 400;              // max buckets (N <= 102400)
constexpr int HWL  = 12800;            // nibble hist words (N <= 102400)
constexpr int SBUF = 8960;             // per-bucket LDS capacity (int), mean 8192, >4 sigma
constexpr int ITER = 9;                // ceil(SBUF/TPBW)

// ---------------- fused: per-slice col bucket counts + row nibble histogram
__global__ __launch_bounds__(TPBW)
void k_prep2(const int* __restrict__ ei, int E, int sliceLen, int W, int NBKT,
             unsigned int* __restrict__ partialR, int* __restrict__ cntTab) {
    __shared__ unsigned int lh[HWL];
    __shared__ int cl[MAXB];
    const int p = blockIdx.x;
    for (int t = threadIdx.x; t < W; t += TPBW) lh[t] = 0;
    for (int t = threadIdx.x; t < NBKT; t += TPBW) cl[t] = 0;
    __syncthreads();
    const int* colA = ei + E;
    const int s = p * sliceLen, send = min(s + sliceLen, E);
    for (int e = s + threadIdx.x; e < send; e += TPBW) {
        int r = ei[e], c = colA[e];
        atomicAdd(&lh[r >> 3], 1u << ((r & 7) * 4));   // per-slice count <= ~7 < 15
        atomicAdd(&cl[c >> BSH], 1);
    }
    __syncthreads();
    for (int w = threadIdx.x; w < W; w += TPBW) partialR[(size_t)p * W + w] = lh[w];
    for (int b = threadIdx.x; b < NBKT; b += TPBW) cntTab[b * PS + p] = cl[b];
}

// ---------------------------------------------- hierarchical scan of cntTab
__global__ void k_scanB1(int* __restrict__ tab, int total, int* __restrict__ bs) {
    __shared__ int tmp[2][1024];
    const int t = threadIdx.x, idx = blockIdx.x * 1024 + t;
    int v = (idx < total) ? tab[idx] : 0;
    int buf = 0;
    tmp[0][t] = v;
    __syncthreads();
    for (int off = 1; off < 1024; off <<= 1) {
        int nv = tmp[buf][t] + ((t >= off) ? tmp[buf][t - off] : 0);
        buf ^= 1; tmp[buf][t] = nv;
        __syncthreads();
    }
    int incl = tmp[buf][t];
    if (idx < total) tab[idx] = incl - v;
    if (t == 1023) bs[blockIdx.x] = incl;
}

__global__ void k_scan2(int* __restrict__ bsum, int NB) {
    __shared__ int tmp[2][256];
    __shared__ int carry_s;
    int t = threadIdx.x;
    if (t == 0) carry_s = 0;
    __syncthreads();
    for (int chunk = 0; chunk < NB; chunk += 256) {
        int idx = chunk + t;
        int v = (idx < NB) ? bsum[idx] : 0;
        int buf = 0;
        tmp[0][t] = v;
        __syncthreads();
        for (int off = 1; off < 256; off <<= 1) {
            int nv = tmp[buf][t] + ((t >= off) ? tmp[buf][t - off] : 0);
            buf ^= 1; tmp[buf][t] = nv;
            __syncthreads();
        }
        int incl = tmp[buf][t];
        int carry = carry_s;
        if (idx < NB) bsum[idx] = carry + incl - v;
        __syncthreads();
        if (t == 255) carry_s = carry + incl;
        __syncthreads();
    }
}

__global__ void k_scanB3(int* __restrict__ tab, int total, const int* __restrict__ bs,
                         int* __restrict__ segBase, int NBKT, int E) {
    const int idx = blockIdx.x * 1024 + threadIdx.x;
    if (idx < total) {
        int v = tab[idx] + bs[blockIdx.x];
        tab[idx] = v;
        if ((idx & (PS - 1)) == 0) segBase[idx / PS] = v;
    }
    if (idx == 0) segBase[NBKT] = E;
}

// ----------------- reduce row partials -> dis + packed xd = {x0,x1,x2,dis}
__global__ void k_xd(const unsigned int* __restrict__ partialR, int W, int N,
                     const float* __restrict__ x,
                     float* __restrict__ dis, float4* __restrict__ xd) {
    const int w = blockIdx.x * blockDim.x + threadIdx.x;
    if (w >= W) return;
    const unsigned int* pr = partialR + w;
    unsigned int accA = 0, accB = 0;            // byte lanes, totals <= ~66
    for (int p = 0; p < PS; p++) {
        unsigned int v = pr[(size_t)p * W];
        accA += v & 0x0F0F0F0Fu;
        accB += (v >> 4) & 0x0F0F0F0Fu;
    }
    int d[8];
    d[0] = accA & 255; d[2] = (accA >> 8) & 255;
    d[4] = (accA >> 16) & 255; d[6] = accA >> 24;
    d[1] = accB & 255; d[3] = (accB >> 8) & 255;
    d[5] = (accB >> 16) & 255; d[7] = accB >> 24;
    const int n0 = w * 8;
#pragma unroll
    for (int k = 0; k < 8; k++) {
        int n = n0 + k;
        if (n < N) {
            float dv = d[k] ? rsqrtf((float)d[k]) : 0.f;
            dis[n] = dv;
            xd[n] = make_float4(x[3 * (long)n], x[3 * (long)n + 1],
                                x[3 * (long)n + 2], dv);
        }
    }
}

// ------------------- stage into bucket-major runs (12B: {id, ea.x, ea.y})
__global__ __launch_bounds__(TPBW)
void k_stage(const int* __restrict__ ei, const float2* __restrict__ ea,
             int E, int sliceLen, const int* __restrict__ cntTab, int NBKT,
             int3* __restrict__ staged) {
    __shared__ int lb[MAXB], lbase[MAXB];
    const int p = blockIdx.x;
    for (int t = threadIdx.x; t < NBKT; t += TPBW) {
        lb[t] = 0;
        lbase[t] = cntTab[t * PS + p];
    }
    __syncthreads();
    const int* colA = ei + E;
    const int s = p * sliceLen, send = min(s + sliceLen, E);
    for (int e = s + threadIdx.x; e < send; e += TPBW) {
        int c = colA[e], r = ei[e];
        int b = c >> BSH;
        int pos = lbase[b] + atomicAdd(&lb[b], 1);
        float2 ev = ea[e];
        int3 o;
        o.x = (r << BSH) | (c & (BKN - 1));
        o.y = __float_as_int(ev.x);
        o.z = __float_as_int(ev.y);
        staged[pos] = o;
    }
}

// --- sortA: in-LDS counting sort (4B/edge) + ea sums + fused layer-1 -> h,
//     sequential sorted-rec writeout; writes base/cnt for g2.
__global__ __launch_bounds__(TPBW)
void k_sortA(const int3* __restrict__ staged, const int* __restrict__ segBase,
             const float* __restrict__ dis, const float4* __restrict__ xd, int N,
             const float* __restrict__ Wc, const float* __restrict__ bc,
             const float* __restrict__ Wn,
             float* __restrict__ h, float2* __restrict__ eaS,
             int* __restrict__ cnt, int* __restrict__ base, int2* __restrict__ rec) {
    __shared__ int sbuf[SBUF];
    __shared__ int lfill[BKN], lexc[BKN], tmp[2][BKN];
    __shared__ float lacx[BKN], lacy[BKN], ldisc[BKN];
    __shared__ float sax[BKN], say[BKN], saz[BKN];
    __shared__ float sWc[48], sbc[16], sWn[80];
    const int b = blockIdx.x, t = threadIdx.x;
    const int s0 = segBase[b], s1 = segBase[b + 1], c0 = b << BSH;
    if (t < BKN) {
        lfill[t] = 0; lacx[t] = 0.f; lacy[t] = 0.f;
        ldisc[t] = (c0 + t < N) ? dis[c0 + t] : 0.f;
    }
    if (t < 48) sWc[t] = Wc[t];
    if (t >= 64 && t < 80) sbc[t - 64] = bc[t - 64];
    if (t >= 128 && t < 208) sWn[t - 128] = Wn[t - 128];
    __syncthreads();
    int rid[ITER], rk[ITER];
#pragma unroll
    for (int k = 0; k < ITER; k++) {
        int e = s0 + t + k * TPBW;
        rk[k] = -1;
        if (e < s1) {
            int3 v = staged[e];
            int j = v.x & (BKN - 1);
            int r = ((unsigned)v.x) >> BSH;
            float nrm = dis[r] * ldisc[j];
            rid[k] = v.x;
            rk[k] = atomicAdd(&lfill[j], 1);
            unsafeAtomicAdd(&lacx[j], nrm * __int_as_float(v.y));
            unsafeAtomicAdd(&lacy[j], nrm * __int_as_float(v.z));
        }
    }
    __syncthreads();
    int buf = 0;
    if (t < BKN) tmp[0][t] = lfill[t];
    __syncthreads();
    for (int off = 1; off < BKN; off <<= 1) {
        if (t < BKN) {
            int nv = tmp[buf][t] + ((t >= off) ? tmp[buf][t - off] : 0);
            tmp[buf ^ 1][t] = nv;
        }
        __syncthreads();
        buf ^= 1;
    }
    if (t < BKN) {
        lexc[t] = tmp[buf][t] - lfill[t];
        int node = c0 + t;
        if (node < N) { cnt[node] = lfill[t]; base[node] = s0 + lexc[t]; }
    }
    __syncthreads();
#pragma unroll
    for (int k = 0; k < ITER; k++) {
        if (rk[k] >= 0) {
            int j = rid[k] & (BKN - 1);
            int pos = lexc[j] + rk[k];
            if (pos < SBUF) sbuf[pos] = ((unsigned)rid[k]) >> BSH;
        }
    }
    __syncthreads();
    // owner-walk: 4 lanes per node; xd gather gives x AND dis in one 16B load
    const int grp = t >> 2, sub = t & 3;     // grp in [0,256)
    const int node = c0 + grp;
    float a0 = 0.f, a1 = 0.f, a2 = 0.f;
    {
        int e0 = lexc[grp], dg = lfill[grp];
        float dc = ldisc[grp];
        if (node < N) {
            for (int e = sub; e < dg; e += 4) {
                int r = sbuf[e0 + e];
                float4 q = xd[r];
                float nrm = q.w * dc;
                a0 += nrm * q.x;
                a1 += nrm * q.y;
                a2 += nrm * q.z;
                rec[s0 + e0 + e] = make_int2(r, __float_as_int(nrm));
            }
        }
    }
    a0 += __shfl_down(a0, 2, 4); a0 += __shfl_down(a0, 1, 4);
    a1 += __shfl_down(a1, 2, 4); a1 += __shfl_down(a1, 1, 4);
    a2 += __shfl_down(a2, 2, 4); a2 += __shfl_down(a2, 1, 4);
    if (sub == 0) { sax[grp] = a0; say[grp] = a1; saz[grp] = a2; }
    __syncthreads();
    if (t < BKN) {
        int nd = c0 + t;
        if (nd < N) {
            float inv = 1.0f / fmaxf((float)lfill[t], 1.0f);
            float m[5] = {sax[t] * inv, say[t] * inv, saz[t] * inv,
                          lacx[t] * inv, lacy[t] * inv};
            float4 xq = xd[nd];
            float xv[3] = {xq.x, xq.y, xq.z};
            float o[16];
#pragma unroll
            for (int k = 0; k < 16; k++) {
                float v = sbc[k];
#pragma unroll
                for (int j = 0; j < 3; j++) v += xv[j] * sWc[j * 16 + k];
#pragma unroll
                for (int j = 0; j < 5; j++) v += m[j] * sWn[j * 16 + k];
                o[k] = fmaxf(v, 0.0f);
            }
            float4* hp = (float4*)(h + 16 * (long)nd);
#pragma unroll
            for (int q = 0; q < 4; q++)
                hp[q] = make_float4(o[4 * q], o[4 * q + 1], o[4 * q + 2], o[4 * q + 3]);
            eaS[nd] = make_float2(lacx[t], lacy[t]);
        }
    }
}

// ---- g2: direct global CSR owner-walk (rec sorted) + node update + pooling
__global__ __launch_bounds__(TPBW)
void k_g2(const int2* __restrict__ rec, const int* __restrict__ base,
          const int* __restrict__ cnt, const float* __restrict__ h,
          const float2* __restrict__ eaS, const int* __restrict__ batch, int N,
          const float* __restrict__ Wc, const float* __restrict__ bc,
          const float* __restrict__ Wn,
          float* __restrict__ pool, int* __restrict__ poolcnt) {
    __shared__ float smr[GKN][17];
    __shared__ float sWc[256], sbc[16], sWn[288], sp[1024];
    __shared__ int sc[64];
    const int b = blockIdx.x, t = threadIdx.x;
    const int c0 = b * GKN;
    for (int k = t; k < 256; k += TPBW) sWc[k] = Wc[k];
    for (int k = t; k < 16;  k += TPBW) sbc[k] = bc[k];
    for (int k = t; k < 288; k += TPBW) sWn[k] = Wn[k];
    for (int k = t; k < 1024; k += TPBW) sp[k] = 0.f;
    if (t < 64) sc[t] = 0;
    __syncthreads();
    const int grp = t >> 3, sub = t & 7;
    const int node = c0 + grp;
    float mm[16];
#pragma unroll
    for (int k = 0; k < 16; k++) mm[k] = 0.f;
    if (node < N) {
        const int2* rp = rec + base[node];
        int dg = cnt[node];
        for (int e = sub; e < dg; e += 8) {
            int2 rv = rp[e];
            float nrm = __int_as_float(rv.y);
            const float4* hr = (const float4*)(h + 16 * (long)rv.x);
            float4 h0 = hr[0], h1 = hr[1], h2 = hr[2], h3 = hr[3];
            mm[0]  += nrm * h0.x;  mm[1]  += nrm * h0.y;
            mm[2]  += nrm * h0.z;  mm[3]  += nrm * h0.w;
            mm[4]  += nrm * h1.x;  mm[5]  += nrm * h1.y;
            mm[6]  += nrm * h1.z;  mm[7]  += nrm * h1.w;
            mm[8]  += nrm * h2.x;  mm[9]  += nrm * h2.y;
            mm[10] += nrm * h2.z;  mm[11] += nrm * h2.w;
            mm[12] += nrm * h3.x;  mm[13] += nrm * h3.y;
            mm[14] += nrm * h3.z;  mm[15] += nrm * h3.w;
        }
    }
#pragma unroll
    for (int k = 0; k < 16; k++) {
        mm[k] += __shfl_down(mm[k], 4, 8);
        mm[k] += __shfl_down(mm[k], 2, 8);
        mm[k] += __shfl_down(mm[k], 1, 8);
    }
    if (sub == 0) {
#pragma unroll
        for (int k = 0; k < 16; k++) smr[grp][k] = mm[k];
    }
    __syncthreads();
    if (t < GKN) {
        int nd = c0 + t;
        if (nd < N) {
            float inv = 1.0f / fmaxf((float)cnt[nd], 1.0f);
            float m[18];
#pragma unroll
            for (int k = 0; k < 16; k++) m[k] = smr[t][k] * inv;
            float2 es = eaS[nd];
            m[16] = es.x * inv; m[17] = es.y * inv;
            float hv[16];
            const float4* hp = (const float4*)(h + 16 * (long)nd);
#pragma unroll
            for (int q = 0; q < 4; q++) {
                float4 t4 = hp[q];
                hv[4 * q] = t4.x; hv[4 * q + 1] = t4.y;
                hv[4 * q + 2] = t4.z; hv[4 * q + 3] = t4.w;
            }
            int g = batch[nd];
            atomicAdd(&sc[g], 1);
#pragma unroll
            for (int k = 0; k < 16; k++) {
                float v = sbc[k];
#pragma unroll
                for (int j = 0; j < 16; j++) v += hv[j] * sWc[j * 16 + k];
#pragma unroll
                for (int j = 0; j < 18; j++) v += m[j] * sWn[j * 16 + k];
                v = fmaxf(v, 0.0f);
                unsafeAtomicAdd(&sp[g * 16 + k], v);
            }
        }
    }
    __syncthreads();
    for (int k = t; k < 1024; k += TPBW)
        if (sp[k] != 0.0f) unsafeAtomicAdd(&pool[k], sp[k]);
    if (t < 64 && sc[t]) atomicAdd(&poolcnt[t], sc[t]);
}

// ---------------------------------------------------------------- MLP head
__global__ void k_final(const float* __restrict__ pool, const int* __restrict__ poolcnt,
                        const float* __restrict__ Wl1, const float* __restrict__ bl1,
                        const float* __restrict__ Wl2, const float* __restrict__ bl2,
                        float* __restrict__ out) {
    int g = threadIdx.x;
    if (g >= 64) return;
    float inv = 1.0f / fmaxf((float)poolcnt[g], 1.0f);
    float gv[16];
#pragma unroll
    for (int k = 0; k < 16; k++) gv[k] = pool[g * 16 + k] * inv;
    float t[16];
#pragma unroll
    for (int k = 0; k < 16; k++) {
        float v = bl1[k];
#pragma unroll
        for (int j = 0; j < 16; j++) v += gv[j] * Wl1[j * 16 + k];
        t[k] = fmaxf(v, 0.0f);
    }
    float o0 = bl2[0], o1 = bl2[1];
#pragma unroll
    for (int j = 0; j < 16; j++) {
        o0 += t[j] * Wl2[j * 2 + 0];
        o1 += t[j] * Wl2[j * 2 + 1];
    }
    out[2 * g + 0] = o0;
    out[2 * g + 1] = o1;
}

extern "C" void kernel_launch(void* const* d_in, const int* in_sizes, int n_in,
                              void* d_out, int out_size, void* d_ws, size_t ws_size,
                              hipStream_t stream) {
    const float* x     = (const float*)d_in[0];
    const int*   ei    = (const int*)  d_in[1];
    const float* ea    = (const float*)d_in[2];
    const int*   batch = (const int*)  d_in[3];
    const float* Wc1   = (const float*)d_in[4];
    const float* bc1   = (const float*)d_in[5];
    const float* Wn1   = (const float*)d_in[6];
    const float* Wc2   = (const float*)d_in[7];
    const float* bc2   = (const float*)d_in[8];
    const float* Wn2   = (const float*)d_in[9];
    const float* Wl1   = (const float*)d_in[10];
    const float* bl1   = (const float*)d_in[11];
    const float* Wl2   = (const float*)d_in[12];
    const float* bl2   = (const float*)d_in[13];
    float* out = (float*)d_out;

    const int N  = in_sizes[0] / 3;
    const int E  = in_sizes[1] / 2;
    const int NBKT = (N + BKN - 1) >> BSH;        // <= 400 for N <= 102400
    const int NG   = (N + GKN - 1) / GKN;         // g2 blocks
    const int W  = (N + 7) >> 3;                  // <= 12800
    const int total = NBKT * PS;
    const int NSB = (total + 1023) / 1024;
    const int sliceLen = (E + PS - 1) / PS;

    char* ws = (char*)d_ws;
    size_t o = 0;
    auto alloc = [&](size_t bytes) {
        void* p = ws + o;
        o += (bytes + 255) & ~(size_t)255;
        return p;
    };
    // zeroed region (pool + poolcnt only)
    float* pool    = (float*)alloc(64 * 16 * 4);
    int*   poolcnt = (int*)  alloc(64 * 4);
    size_t zbytes = o;
    // non-zeroed
    float*  dis     = (float*)alloc((size_t)N * 4);
    float4* xd      = (float4*)alloc((size_t)N * 16);
    int*    cnt     = (int*)  alloc((size_t)N * 4);
    int*    base    = (int*)  alloc((size_t)N * 4);
    float2* eaS     = (float2*)alloc((size_t)N * 8);
    int*    cntTab  = (int*)  alloc((size_t)total * 4);
    int*    bs      = (int*)  alloc((size_t)NSB * 4);
    int*    segBase = (int*)  alloc((size_t)(NBKT + 1) * 4);
    // region B: partialR [prep2..xd] then rec [sortA..g2] (disjoint lifetimes)
    size_t szPR = (size_t)PS * W * 4, szRC = (size_t)E * 8;
    char* regionB = (char*)alloc(szPR > szRC ? szPR : szRC);
    unsigned int* partialR = (unsigned int*)regionB;
    int2* rec = (int2*)regionB;
    // staged: alive stage..sortA
    int3* staged = (int3*)alloc((size_t)E * 12);
    float* h = (float*)alloc((size_t)N * 16 * 4);
    (void)ws_size;

    hipMemsetAsync(d_ws, 0, zbytes, stream);

    k_prep2 <<<PS, TPBW, 0, stream>>>(ei, E, sliceLen, W, NBKT, partialR, cntTab);
    k_scanB1<<<NSB, 1024, 0, stream>>>(cntTab, total, bs);
    k_scan2 <<<1, 256, 0, stream>>>(bs, NSB);
    k_scanB3<<<NSB, 1024, 0, stream>>>(cntTab, total, bs, segBase, NBKT, E);
    k_xd    <<<(W + TPB - 1) / TPB, TPB, 0, stream>>>(partialR, W, N, x, dis, xd);
    k_stage <<<PS, TPBW, 0, stream>>>(ei, (const float2*)ea, E, sliceLen,
                                      cntTab, NBKT, staged);
    k_sortA <<<NBKT, TPBW, 0, stream>>>(staged, segBase, dis, xd, N,
                                        Wc1, bc1, Wn1, h, eaS, cnt, base, rec);
    k_g2    <<<NG, TPBW, 0, stream>>>(rec, base, cnt, h, eaS, batch, N,
                                      Wc2, bc2, Wn2, pool, poolcnt);
    k_final <<<1, 64, 0, stream>>>(pool, poolcnt, Wl1, bl1, Wl2, bl2, out);
}

// Round 14
// 321.391 us; speedup vs baseline: 1.4312x; 1.0840x over previous
//
#include <hip/hip_runtime.h>

constexpr int TPB  = 256;
constexpr int TPBW = 1024;
constexpr int PS   = 256;              // edge slices (1 stage block/CU, long runs)
constexpr int BSH  = 8;                // 256-node buckets for staging/sort
constexpr int BKN  = 256;
constexpr int GKN  = 128;              // g2 nodes per block
constexpr int MAXB = 400;              // max buckets (N <= 102400)
constexpr int HWL  = 12800;            // nibble hist words (N <= 102400)
constexpr int SBUF = 8960;             // per-bucket LDS capacity (int), mean 8192, >4 sigma
constexpr int ITER = 9;                // ceil(SBUF/TPBW)

__device__ __forceinline__ unsigned short f2bf(float f) {
    unsigned u = __float_as_uint(f);
    u += 0x7FFFu + ((u >> 16) & 1u);
    return (unsigned short)(u >> 16);
}
__device__ __forceinline__ float bflo(unsigned u) {       // low 16 bits -> f32
    return __uint_as_float(u << 16);
}
__device__ __forceinline__ float bfhi(unsigned u) {       // high 16 bits -> f32
    return __uint_as_float(u & 0xFFFF0000u);
}

// ---------------- fused: per-slice col bucket counts + row nibble histogram
__global__ __launch_bounds__(TPBW)
void k_prep2(const int* __restrict__ ei, int E, int sliceLen, int W, int NBKT,
             unsigned int* __restrict__ partialR, int* __restrict__ cntTab) {
    __shared__ unsigned int lh[HWL];
    __shared__ int cl[MAXB];
    const int p = blockIdx.x;
    for (int t = threadIdx.x; t < W; t += TPBW) lh[t] = 0;
    for (int t = threadIdx.x; t < NBKT; t += TPBW) cl[t] = 0;
    __syncthreads();
    const int* colA = ei + E;
    const int s = p * sliceLen, send = min(s + sliceLen, E);
    for (int e = s + threadIdx.x; e < send; e += TPBW) {
        int r = ei[e], c = colA[e];
        atomicAdd(&lh[r >> 3], 1u << ((r & 7) * 4));   // per-slice count <= ~7 < 15
        atomicAdd(&cl[c >> BSH], 1);
    }
    __syncthreads();
    for (int w = threadIdx.x; w < W; w += TPBW) partialR[(size_t)p * W + w] = lh[w];
    for (int b = threadIdx.x; b < NBKT; b += TPBW) cntTab[b * PS + p] = cl[b];
}

// ---------------------------------------------- hierarchical scan of cntTab
__global__ void k_scanB1(int* __restrict__ tab, int total, int* __restrict__ bs) {
    __shared__ int tmp[2][1024];
    const int t = threadIdx.x, idx = blockIdx.x * 1024 + t;
    int v = (idx < total) ? tab[idx] : 0;
    int buf = 0;
    tmp[0][t] = v;
    __syncthreads();
    for (int off = 1; off < 1024; off <<= 1) {
        int nv = tmp[buf][t] + ((t >= off) ? tmp[buf][t - off] : 0);
        buf ^= 1; tmp[buf][t] = nv;
        __syncthreads();
    }
    int incl = tmp[buf][t];
    if (idx < total) tab[idx] = incl - v;
    if (t == 1023) bs[blockIdx.x] = incl;
}

__global__ void k_scan2(int* __restrict__ bsum, int NB) {
    __shared__ int tmp[2][256];
    __shared__ int carry_s;
    int t = threadIdx.x;
    if (t == 0) carry_s = 0;
    __syncthreads();
    for (int chunk = 0; chunk < NB; chunk += 256) {
        int idx = chunk + t;
        int v = (idx < NB) ? bsum[idx] : 0;
        int buf = 0;
        tmp[0][t] = v;
        __syncthreads();
        for (int off = 1; off < 256; off <<= 1) {
            int nv = tmp[buf][t] + ((t >= off) ? tmp[buf][t - off] : 0);
            buf ^= 1; tmp[buf][t] = nv;
            __syncthreads();
        }
        int incl = tmp[buf][t];
        int carry = carry_s;
        if (idx < NB) bsum[idx] = carry + incl - v;
        __syncthreads();
        if (t == 255) carry_s = carry + incl;
        __syncthreads();
    }
}

__global__ void k_scanB3(int* __restrict__ tab, int total, const int* __restrict__ bs,
                         int* __restrict__ segBase, int NBKT, int E) {
    const int idx = blockIdx.x * 1024 + threadIdx.x;
    if (idx < total) {
        int v = tab[idx] + bs[blockIdx.x];
        tab[idx] = v;
        if ((idx & (PS - 1)) == 0) segBase[idx / PS] = v;
    }
    if (idx == 0) segBase[NBKT] = E;
}

// ----------------- reduce row partials -> dis + packed xd = {x0,x1,x2,dis}
__global__ void k_xd(const unsigned int* __restrict__ partialR, int W, int N,
                     const float* __restrict__ x,
                     float* __restrict__ dis, float4* __restrict__ xd) {
    const int w = blockIdx.x * blockDim.x + threadIdx.x;
    if (w >= W) return;
    const unsigned int* pr = partialR + w;
    unsigned int accA = 0, accB = 0;            // byte lanes, totals <= ~66
    for (int p = 0; p < PS; p++) {
        unsigned int v = pr[(size_t)p * W];
        accA += v & 0x0F0F0F0Fu;
        accB += (v >> 4) & 0x0F0F0F0Fu;
    }
    int d[8];
    d[0] = accA & 255; d[2] = (accA >> 8) & 255;
    d[4] = (accA >> 16) & 255; d[6] = accA >> 24;
    d[1] = accB & 255; d[3] = (accB >> 8) & 255;
    d[5] = (accB >> 16) & 255; d[7] = accB >> 24;
    const int n0 = w * 8;
#pragma unroll
    for (int k = 0; k < 8; k++) {
        int n = n0 + k;
        if (n < N) {
            float dv = d[k] ? rsqrtf((float)d[k]) : 0.f;
            dis[n] = dv;
            xd[n] = make_float4(x[3 * (long)n], x[3 * (long)n + 1],
                                x[3 * (long)n + 2], dv);
        }
    }
}

// -------------- stage into bucket-major runs (8B: {id, ea packed bf16x2})
__global__ __launch_bounds__(TPBW)
void k_stage(const int* __restrict__ ei, const float2* __restrict__ ea,
             int E, int sliceLen, const int* __restrict__ cntTab, int NBKT,
             int2* __restrict__ staged) {
    __shared__ int lb[MAXB], lbase[MAXB];
    const int p = blockIdx.x;
    for (int t = threadIdx.x; t < NBKT; t += TPBW) {
        lb[t] = 0;
        lbase[t] = cntTab[t * PS + p];
    }
    __syncthreads();
    const int* colA = ei + E;
    const int s = p * sliceLen, send = min(s + sliceLen, E);
    for (int e = s + threadIdx.x; e < send; e += TPBW) {
        int c = colA[e], r = ei[e];
        int b = c >> BSH;
        int pos = lbase[b] + atomicAdd(&lb[b], 1);
        float2 ev = ea[e];
        unsigned eap = (unsigned)f2bf(ev.x) | ((unsigned)f2bf(ev.y) << 16);
        staged[pos] = make_int2((r << BSH) | (c & (BKN - 1)), (int)eap);
    }
}

// --- sortA: in-LDS counting sort (4B/edge) + ea sums + fused layer-1 -> h(bf16),
//     sequential sorted-rec writeout; writes base/cnt for g2.
__global__ __launch_bounds__(TPBW)
void k_sortA(const int2* __restrict__ staged, const int* __restrict__ segBase,
             const float* __restrict__ dis, const float4* __restrict__ xd, int N,
             const float* __restrict__ Wc, const float* __restrict__ bc,
             const float* __restrict__ Wn,
             unsigned short* __restrict__ hb, float2* __restrict__ eaS,
             int* __restrict__ cnt, int* __restrict__ base, int2* __restrict__ rec) {
    __shared__ int sbuf[SBUF];
    __shared__ int lfill[BKN], lexc[BKN], tmp[2][BKN];
    __shared__ float lacx[BKN], lacy[BKN], ldisc[BKN];
    __shared__ float sax[BKN], say[BKN], saz[BKN];
    __shared__ float sWc[48], sbc[16], sWn[80];
    const int b = blockIdx.x, t = threadIdx.x;
    const int s0 = segBase[b], s1 = segBase[b + 1], c0 = b << BSH;
    if (t < BKN) {
        lfill[t] = 0; lacx[t] = 0.f; lacy[t] = 0.f;
        ldisc[t] = (c0 + t < N) ? dis[c0 + t] : 0.f;
    }
    if (t < 48) sWc[t] = Wc[t];
    if (t >= 64 && t < 80) sbc[t - 64] = bc[t - 64];
    if (t >= 128 && t < 208) sWn[t - 128] = Wn[t - 128];
    __syncthreads();
    int rid[ITER], rk[ITER];
#pragma unroll
    for (int k = 0; k < ITER; k++) {
        int e = s0 + t + k * TPBW;
        rk[k] = -1;
        if (e < s1) {
            int2 v = staged[e];
            int j = v.x & (BKN - 1);
            int r = ((unsigned)v.x) >> BSH;
            float nrm = dis[r] * ldisc[j];
            rid[k] = v.x;
            rk[k] = atomicAdd(&lfill[j], 1);
            unsafeAtomicAdd(&lacx[j], nrm * bflo((unsigned)v.y));
            unsafeAtomicAdd(&lacy[j], nrm * bfhi((unsigned)v.y));
        }
    }
    __syncthreads();
    int buf = 0;
    if (t < BKN) tmp[0][t] = lfill[t];
    __syncthreads();
    for (int off = 1; off < BKN; off <<= 1) {
        if (t < BKN) {
            int nv = tmp[buf][t] + ((t >= off) ? tmp[buf][t - off] : 0);
            tmp[buf ^ 1][t] = nv;
        }
        __syncthreads();
        buf ^= 1;
    }
    if (t < BKN) {
        lexc[t] = tmp[buf][t] - lfill[t];
        int node = c0 + t;
        if (node < N) { cnt[node] = lfill[t]; base[node] = s0 + lexc[t]; }
    }
    __syncthreads();
#pragma unroll
    for (int k = 0; k < ITER; k++) {
        if (rk[k] >= 0) {
            int j = rid[k] & (BKN - 1);
            int pos = lexc[j] + rk[k];
            if (pos < SBUF) sbuf[pos] = ((unsigned)rid[k]) >> BSH;
        }
    }
    __syncthreads();
    // owner-walk: 4 lanes per node; xd gather gives x AND dis in one 16B load
    const int grp = t >> 2, sub = t & 3;     // grp in [0,256)
    const int node = c0 + grp;
    float a0 = 0.f, a1 = 0.f, a2 = 0.f;
    {
        int e0 = lexc[grp], dg = lfill[grp];
        float dc = ldisc[grp];
        if (node < N) {
            for (int e = sub; e < dg; e += 4) {
                int r = sbuf[e0 + e];
                float4 q = xd[r];
                float nrm = q.w * dc;
                a0 += nrm * q.x;
                a1 += nrm * q.y;
                a2 += nrm * q.z;
                rec[s0 + e0 + e] = make_int2(r, __float_as_int(nrm));
            }
        }
    }
    a0 += __shfl_down(a0, 2, 4); a0 += __shfl_down(a0, 1, 4);
    a1 += __shfl_down(a1, 2, 4); a1 += __shfl_down(a1, 1, 4);
    a2 += __shfl_down(a2, 2, 4); a2 += __shfl_down(a2, 1, 4);
    if (sub == 0) { sax[grp] = a0; say[grp] = a1; saz[grp] = a2; }
    __syncthreads();
    if (t < BKN) {
        int nd = c0 + t;
        if (nd < N) {
            float inv = 1.0f / fmaxf((float)lfill[t], 1.0f);
            float m[5] = {sax[t] * inv, say[t] * inv, saz[t] * inv,
                          lacx[t] * inv, lacy[t] * inv};
            float4 xq = xd[nd];
            float xv[3] = {xq.x, xq.y, xq.z};
            float o[16];
#pragma unroll
            for (int k = 0; k < 16; k++) {
                float v = sbc[k];
#pragma unroll
                for (int j = 0; j < 3; j++) v += xv[j] * sWc[j * 16 + k];
#pragma unroll
                for (int j = 0; j < 5; j++) v += m[j] * sWn[j * 16 + k];
                o[k] = fmaxf(v, 0.0f);
            }
            unsigned ov[8];
#pragma unroll
            for (int q = 0; q < 8; q++)
                ov[q] = (unsigned)f2bf(o[2 * q]) | ((unsigned)f2bf(o[2 * q + 1]) << 16);
            uint4* hp = (uint4*)(hb + 16 * (size_t)nd);
            hp[0] = make_uint4(ov[0], ov[1], ov[2], ov[3]);
            hp[1] = make_uint4(ov[4], ov[5], ov[6], ov[7]);
            eaS[nd] = make_float2(lacx[t], lacy[t]);
        }
    }
}

// ---- g2: global CSR owner-walk over bf16 h + node update + pooling (fused)
__global__ __launch_bounds__(TPBW)
void k_g2(const int2* __restrict__ rec, const int* __restrict__ base,
          const int* __restrict__ cnt, const unsigned short* __restrict__ hb,
          const float2* __restrict__ eaS, const int* __restrict__ batch, int N,
          const float* __restrict__ Wc, const float* __restrict__ bc,
          const float* __restrict__ Wn,
          float* __restrict__ pool, int* __restrict__ poolcnt) {
    __shared__ float smr[GKN][17];
    __shared__ float sWc[256], sbc[16], sWn[288], sp[1024];
    __shared__ int sc[64];
    const int b = blockIdx.x, t = threadIdx.x;
    const int c0 = b * GKN;
    for (int k = t; k < 256; k += TPBW) sWc[k] = Wc[k];
    for (int k = t; k < 16;  k += TPBW) sbc[k] = bc[k];
    for (int k = t; k < 288; k += TPBW) sWn[k] = Wn[k];
    for (int k = t; k < 1024; k += TPBW) sp[k] = 0.f;
    if (t < 64) sc[t] = 0;
    __syncthreads();
    const int grp = t >> 3, sub = t & 7;
    const int node = c0 + grp;
    float mm[16];
#pragma unroll
    for (int k = 0; k < 16; k++) mm[k] = 0.f;
    if (node < N) {
        const int2* rp = rec + base[node];
        int dg = cnt[node];
        for (int e = sub; e < dg; e += 8) {
            int2 rv = rp[e];
            float nrm = __int_as_float(rv.y);
            const uint4* hr = (const uint4*)(hb + 16 * (size_t)rv.x);
            uint4 A = hr[0], B = hr[1];
            mm[0]  += nrm * bflo(A.x);  mm[1]  += nrm * bfhi(A.x);
            mm[2]  += nrm * bflo(A.y);  mm[3]  += nrm * bfhi(A.y);
            mm[4]  += nrm * bflo(A.z);  mm[5]  += nrm * bfhi(A.z);
            mm[6]  += nrm * bflo(A.w);  mm[7]  += nrm * bfhi(A.w);
            mm[8]  += nrm * bflo(B.x);  mm[9]  += nrm * bfhi(B.x);
            mm[10] += nrm * bflo(B.y);  mm[11] += nrm * bfhi(B.y);
            mm[12] += nrm * bflo(B.z);  mm[13] += nrm * bfhi(B.z);
            mm[14] += nrm * bflo(B.w);  mm[15] += nrm * bfhi(B.w);
        }
    }
#pragma unroll
    for (int k = 0; k < 16; k++) {
        mm[k] += __shfl_down(mm[k], 4, 8);
        mm[k] += __shfl_down(mm[k], 2, 8);
        mm[k] += __shfl_down(mm[k], 1, 8);
    }
    if (sub == 0) {
#pragma unroll
        for (int k = 0; k < 16; k++) smr[grp][k] = mm[k];
    }
    __syncthreads();
    if (t < GKN) {
        int nd = c0 + t;
        if (nd < N) {
            float inv = 1.0f / fmaxf((float)cnt[nd], 1.0f);
            float m[18];
#pragma unroll
            for (int k = 0; k < 16; k++) m[k] = smr[t][k] * inv;
            float2 es = eaS[nd];
            m[16] = es.x * inv; m[17] = es.y * inv;
            const uint4* hp = (const uint4*)(hb + 16 * (size_t)nd);
            uint4 A = hp[0], B = hp[1];
            float hv[16] = {bflo(A.x), bfhi(A.x), bflo(A.y), bfhi(A.y),
                            bflo(A.z), bfhi(A.z), bflo(A.w), bfhi(A.w),
                            bflo(B.x), bfhi(B.x), bflo(B.y), bfhi(B.y),
                            bflo(B.z), bfhi(B.z), bflo(B.w), bfhi(B.w)};
            int g = batch[nd];
            atomicAdd(&sc[g], 1);
#pragma unroll
            for (int k = 0; k < 16; k++) {
                float v = sbc[k];
#pragma unroll
                for (int j = 0; j < 16; j++) v += hv[j] * sWc[j * 16 + k];
#pragma unroll
                for (int j = 0; j < 18; j++) v += m[j] * sWn[j * 16 + k];
                v = fmaxf(v, 0.0f);
                unsafeAtomicAdd(&sp[g * 16 + k], v);
            }
        }
    }
    __syncthreads();
    for (int k = t; k < 1024; k += TPBW)
        if (sp[k] != 0.0f) unsafeAtomicAdd(&pool[k], sp[k]);
    if (t < 64 && sc[t]) atomicAdd(&poolcnt[t], sc[t]);
}

// ---------------------------------------------------------------- MLP head
__global__ void k_final(const float* __restrict__ pool, const int* __restrict__ poolcnt,
                        const float* __restrict__ Wl1, const float* __restrict__ bl1,
                        const float* __restrict__ Wl2, const float* __restrict__ bl2,
                        float* __restrict__ out) {
    int g = threadIdx.x;
    if (g >= 64) return;
    float inv = 1.0f / fmaxf((float)poolcnt[g], 1.0f);
    float gv[16];
#pragma unroll
    for (int k = 0; k < 16; k++) gv[k] = pool[g * 16 + k] * inv;
    float t[16];
#pragma unroll
    for (int k = 0; k < 16; k++) {
        float v = bl1[k];
#pragma unroll
        for (int j = 0; j < 16; j++) v += gv[j] * Wl1[j * 16 + k];
        t[k] = fmaxf(v, 0.0f);
    }
    float o0 = bl2[0], o1 = bl2[1];
#pragma unroll
    for (int j = 0; j < 16; j++) {
        o0 += t[j] * Wl2[j * 2 + 0];
        o1 += t[j] * Wl2[j * 2 + 1];
    }
    out[2 * g + 0] = o0;
    out[2 * g + 1] = o1;
}

extern "C" void kernel_launch(void* const* d_in, const int* in_sizes, int n_in,
                              void* d_out, int out_size, void* d_ws, size_t ws_size,
                              hipStream_t stream) {
    const float* x     = (const float*)d_in[0];
    const int*   ei    = (const int*)  d_in[1];
    const float* ea    = (const float*)d_in[2];
    const int*   batch = (const int*)  d_in[3];
    const float* Wc1   = (const float*)d_in[4];
    const float* bc1   = (const float*)d_in[5];
    const float* Wn1   = (const float*)d_in[6];
    const float* Wc2   = (const float*)d_in[7];
    const float* bc2   = (const float*)d_in[8];
    const float* Wn2   = (const float*)d_in[9];
    const float* Wl1   = (const float*)d_in[10];
    const float* bl1   = (const float*)d_in[11];
    const float* Wl2   = (const float*)d_in[12];
    const float* bl2   = (const float*)d_in[13];
    float* out = (float*)d_out;

    const int N  = in_sizes[0] / 3;
    const int E  = in_sizes[1] / 2;
    const int NBKT = (N + BKN - 1) >> BSH;        // <= 400 for N <= 102400
    const int NG   = (N + GKN - 1) / GKN;         // g2 blocks
    const int W  = (N + 7) >> 3;                  // <= 12800
    const int total = NBKT * PS;
    const int NSB = (total + 1023) / 1024;
    const int sliceLen = (E + PS - 1) / PS;

    char* ws = (char*)d_ws;
    size_t o = 0;
    auto alloc = [&](size_t bytes) {
        void* p = ws + o;
        o += (bytes + 255) & ~(size_t)255;
        return p;
    };
    // zeroed region (pool + poolcnt only)
    float* pool    = (float*)alloc(64 * 16 * 4);
    int*   poolcnt = (int*)  alloc(64 * 4);
    size_t zbytes = o;
    // non-zeroed
    float*  dis     = (float*)alloc((size_t)N * 4);
    float4* xd      = (float4*)alloc((size_t)N * 16);
    int*    cnt     = (int*)  alloc((size_t)N * 4);
    int*    base    = (int*)  alloc((size_t)N * 4);
    float2* eaS     = (float2*)alloc((size_t)N * 8);
    int*    cntTab  = (int*)  alloc((size_t)total * 4);
    int*    bs      = (int*)  alloc((size_t)NSB * 4);
    int*    segBase = (int*)  alloc((size_t)(NBKT + 1) * 4);
    // region B: partialR [prep2..xd] then rec [sortA..g2] (disjoint lifetimes)
    size_t szPR = (size_t)PS * W * 4, szRC = (size_t)E * 8;
    char* regionB = (char*)alloc(szPR > szRC ? szPR : szRC);
    unsigned int* partialR = (unsigned int*)regionB;
    int2* rec = (int2*)regionB;
    // staged: alive stage..sortA
    int2* staged = (int2*)alloc((size_t)E * 8);
    // h (bf16): written in sortA, read in g2
    unsigned short* hb = (unsigned short*)alloc((size_t)N * 16 * 2);
    (void)ws_size;

    hipMemsetAsync(d_ws, 0, zbytes, stream);

    k_prep2 <<<PS, TPBW, 0, stream>>>(ei, E, sliceLen, W, NBKT, partialR, cntTab);
    k_scanB1<<<NSB, 1024, 0, stream>>>(cntTab, total, bs);
    k_scan2 <<<1, 256, 0, stream>>>(bs, NSB);
    k_scanB3<<<NSB, 1024, 0, stream>>>(cntTab, total, bs, segBase, NBKT, E);
    k_xd    <<<(W + TPB - 1) / TPB, TPB, 0, stream>>>(partialR, W, N, x, dis, xd);
    k_stage <<<PS, TPBW, 0, stream>>>(ei, (const float2*)ea, E, sliceLen,
                                      cntTab, NBKT, staged);
    k_sortA <<<NBKT, TPBW, 0, stream>>>(staged, segBase, dis, xd, N,
                                        Wc1, bc1, Wn1, hb, eaS, cnt, base, rec);
    k_g2    <<<NG, TPBW, 0, stream>>>(rec, base, cnt, hb, eaS, batch, N,
                                      Wc2, bc2, Wn2, pool, poolcnt);
    k_final <<<1, 64, 0, stream>>>(pool, poolcnt, Wl1, bl1, Wl2, bl2, out);
}